// Round 8
// baseline (385.155 us; speedup 1.0000x reference)
//
#include <hip/hip_runtime.h>

#define N_PTS 262144
#define X_STRIDE 79

// LDS strides in halfs — 16B-aligned rows (R5's odd strides broke b128 vectorization).
#define RSTR 264   // reg2
#define XSTR 152   // bufX

using floatx4   = __attribute__((ext_vector_type(4))) float;
using floatx4a  = __attribute__((ext_vector_type(4), aligned(4))) float;
using floatx16  = __attribute__((ext_vector_type(16))) float;
using half8     = __attribute__((ext_vector_type(8))) _Float16;
using ushort8v  = __attribute__((ext_vector_type(8))) unsigned short;
using uint2v    = __attribute__((ext_vector_type(2))) unsigned int;
using uint4v    = __attribute__((ext_vector_type(4))) unsigned int;

__device__ __forceinline__ unsigned short f2h(float f) {
  _Float16 h = (_Float16)f;
  return __builtin_bit_cast(unsigned short, h);
}
// pack 2 f32 -> 2 f16 in one VALU op (v_cvt_pkrtz_f16_f32)
__device__ __forceinline__ unsigned int pk2(float a, float b) {
  return __builtin_bit_cast(unsigned int, __builtin_amdgcn_cvt_pkrtz(a, b));
}

// ---- weight table: FRAGMENT-MAJOR fp16 -------------------------------------
// Layers 0..10: 32x32x16 A-layout: chunk (j,s,lane) at off+((j*KT+s)*64+lane)*8
//   holds W^T[j*32+(lane&31)][s*16+(lane>>5)*8+0..7], KT=KP/16.
// Layers 11..18: 16x16x32 A-layout: W^T[j*16+(lane&15)][s*32+(lane>>4)*8+..],
//   KT=KP/32.  (11=nw8; 12..16 = fw1,fw2,bw1,bw2,bw3 for the front chain;
//   17=uw1X, 18=uw2X for the fused per-point voxel branch.)
__device__ const int T_KS[19]  = {63,64,63,128,128,64,64,140,256,396,256,256,
                                  63,64,128,64,64, 63,128};
__device__ const int T_NS[19]  = {64,64,128,64,64,64,64,256,256,256,256,12,
                                  64,64,64,64,64, 128,64};
__device__ const int T_KP[19]  = {64,64,64,128,128,64,64,144,256,400,256,256,
                                  64,64,128,64,64, 64,128};
__device__ const int T_OFF[20] = {0,4096,8192,16384,24576,32768,36864,40960,
                                  77824,143360,245760,311296,
                                  315392,319488,323584,331776,335872,339968,
                                  348160,356352};
#define OFF_FW1 0
#define OFF_FW2 4096
#define OFF_UW1 8192
#define OFF_UW2 16384
#define OFF_BW1 24576
#define OFF_BW2 32768
#define OFF_BW3 36864
#define OFF_NW0 40960
#define OFF_NW2 77824
#define OFF_NW4 143360
#define OFF_NW6 245760
#define OFF_NW8 311296
#define OFF_FW1X 315392
#define OFF_FW2X 319488
#define OFF_BW1X 323584
#define OFF_BW2X 331776
#define OFF_BW3X 335872
#define OFF_UW1X 339968
#define OFF_UW2X 348160
#define WT_TOTAL 356352
// LDS-relative offsets of the staged front-chain weights (halfs)
#define LF_FW1 0
#define LF_FW2 4096
#define LF_BW1 8192
#define LF_BW2 16384
#define LF_BW3 20480
#define WFRONT_HALFS 24576

// ---- 32x32x16 MFMA accum: D(features x points) = W^T(A) x X^T(B) -----------
// B frag: B[k=(lane>>5)*8+i][pt=lane&31] -> LDS row(point)-major 16B read.
// D: col=pt=lane&31, row=feat=(reg&3)+8*(reg>>2)+4*(lane>>5).
// Plain loop — R2-R6 proved every manual scheduling/staging variant regresses.
template<int NJ, int NM>
__device__ __forceinline__ void accum32(floatx16 (&acc)[NJ][NM],
    const unsigned short* ldsB, int strideB, int mrow0,
    const unsigned short* wtL, int KTtot, int jg0,
    int sBegin, int sEnd, int sBBase) {
  const int lane = threadIdx.x & 63;
  const int pr = lane & 31, h = lane >> 5;
#pragma unroll 4
  for (int s = sBegin; s < sEnd; ++s) {
    half8 b[NM];
#pragma unroll
    for (int m = 0; m < NM; ++m)
      b[m] = *reinterpret_cast<const half8*>(
          ldsB + (mrow0 + m * 32 + pr) * strideB + (s - sBBase) * 16 + h * 8);
#pragma unroll
    for (int j = 0; j < NJ; ++j) {
      half8 w = *reinterpret_cast<const half8*>(
          wtL + (size_t)(((jg0 + j) * KTtot + s) * 64 + lane) * 8);
#pragma unroll
      for (int m = 0; m < NM; ++m)
        acc[j][m] = __builtin_amdgcn_mfma_f32_32x32x16_f16(w, b[m], acc[j][m], 0, 0, 0);
    }
  }
}

template<int NJ, int NM>
__device__ __forceinline__ void zero32(floatx16 (&acc)[NJ][NM]) {
#pragma unroll
  for (int j = 0; j < NJ; ++j)
#pragma unroll
    for (int m = 0; m < NM; ++m)
#pragma unroll
      for (int r = 0; r < 16; ++r) acc[j][m][r] = 0.f;
}

// epilogue: 4 reg-groups per tile; pkrtz-packed ds_write_b64 each.
template<int NJ, int NM>
__device__ __forceinline__ void epi32(const floatx16 (&acc)[NJ][NM],
    unsigned short* ldsOut, int strideO, int colOff, int mrow0,
    const float* bias, int biasBase, bool relu) {
  const int lane = threadIdx.x & 63;
  const int pr = lane & 31, h = lane >> 5;
#pragma unroll
  for (int j = 0; j < NJ; ++j) {
#pragma unroll
    for (int g = 0; g < 4; ++g) {
      floatx4 b4 = *reinterpret_cast<const floatx4*>(bias + biasBase + j * 32 + g * 8 + h * 4);
#pragma unroll
      for (int m = 0; m < NM; ++m) {
        float v0 = acc[j][m][g * 4 + 0] + b4[0];
        float v1 = acc[j][m][g * 4 + 1] + b4[1];
        float v2 = acc[j][m][g * 4 + 2] + b4[2];
        float v3 = acc[j][m][g * 4 + 3] + b4[3];
        if (relu) {
          v0 = fmaxf(v0, 0.f); v1 = fmaxf(v1, 0.f);
          v2 = fmaxf(v2, 0.f); v3 = fmaxf(v3, 0.f);
        }
        uint2v hv; hv[0] = pk2(v0, v1); hv[1] = pk2(v2, v3);
        *reinterpret_cast<uint2v*>(
            ldsOut + (mrow0 + m * 32 + pr) * strideO + colOff + j * 32 + g * 8 + h * 4) = hv;
      }
    }
  }
}

// ---- 16x16x32 path ---------------------------------------------------------
// A frag: A[feat=j*16+(lane&15)][k=s*32+(lane>>4)*8+i]
// B frag: B[k=(lane>>4)*8+i][pt=lane&15]
// D:      col=pt=lane&15, row=feat=(lane>>4)*4+reg   (verified by nw8 path)
__device__ __forceinline__ void accum16(floatx4& acc,
    const unsigned short* ldsB, int strideB, int mrow0,
    const unsigned short* wtL, int sEnd) {
  const int lane = threadIdx.x & 63;
  const int nh = lane & 15, q = lane >> 4;
#pragma unroll
  for (int s = 0; s < 8; ++s) {
    if (s >= sEnd) break;
    half8 b = *reinterpret_cast<const half8*>(
        ldsB + (mrow0 + nh) * strideB + s * 32 + q * 8);
    half8 w = *reinterpret_cast<const half8*>(
        wtL + (size_t)(s * 64 + lane) * 8);
    acc = __builtin_amdgcn_mfma_f32_16x16x32_f16(w, b, acc, 0, 0, 0);
  }
}

// wave-private chain helpers (one wave owns 16 points); NJC = #16-wide j-frags
template<int NJC>
__device__ __forceinline__ void chainZero(floatx4 (&t)[NJC]) {
#pragma unroll
  for (int j = 0; j < NJC; ++j) {
    t[j][0] = 0.f; t[j][1] = 0.f; t[j][2] = 0.f; t[j][3] = 0.f;
  }
}

// rowB = LDS base of this lane's point-row + column base (16B aligned).
// wtL may be LDS (staged) or GLOBAL (L2-resident; per-s j-loads independent).
template<int NJC>
__device__ __forceinline__ void chain_mm(floatx4 (&t)[NJC],
    const unsigned short* rowB, const unsigned short* wtL,
    int KT, int sBegin, int sEnd) {
  const int lane = threadIdx.x & 63;
  const int q = lane >> 4;
#pragma unroll
  for (int s = sBegin; s < sEnd; ++s) {
    half8 b = *reinterpret_cast<const half8*>(rowB + (s - sBegin) * 32 + q * 8);
#pragma unroll
    for (int j = 0; j < NJC; ++j) {
      half8 w = *reinterpret_cast<const half8*>(
          wtL + (size_t)((j * KT + s) * 64 + lane) * 8);
      t[j] = __builtin_amdgcn_mfma_f32_16x16x32_f16(w, b, t[j], 0, 0, 0);
    }
  }
}

// D -> own point-row: feat = j*16 + q*4 + r, 1 ds_write_b64 per j
template<int NJC>
__device__ __forceinline__ void chain_epi(const floatx4 (&t)[NJC],
    unsigned short* rowOut, const float* bias, bool relu) {
  const int lane = threadIdx.x & 63;
  const int q = lane >> 4;
#pragma unroll
  for (int j = 0; j < NJC; ++j) {
    floatx4 b4 = *reinterpret_cast<const floatx4*>(bias + j * 16 + q * 4);
    float v0 = t[j][0] + b4[0], v1 = t[j][1] + b4[1];
    float v2 = t[j][2] + b4[2], v3 = t[j][3] + b4[3];
    if (relu) {
      v0 = fmaxf(v0, 0.f); v1 = fmaxf(v1, 0.f);
      v2 = fmaxf(v2, 0.f); v3 = fmaxf(v3, 0.f);
    }
    uint2v hv; hv[0] = pk2(v0, v1); hv[1] = pk2(v2, v3);
    *reinterpret_cast<uint2v*>(rowOut + j * 16 + q * 4) = hv;
  }
}

// ---- kernel 1: weight repack + scalar output -------------------------------
struct PrepArgs { const float* src[19]; };

__global__ __launch_bounds__(256) void prep_k(PrepArgs a, unsigned short* wt,
                                              float* outM, float Mval) {
  int chunk = blockIdx.x * 256 + threadIdx.x;  // one thread per 8-half chunk
  if (chunk == 0) *outM = Mval;
  if (chunk >= WT_TOTAL / 8) return;
  int gid = chunk * 8;
  int L = 0;
  while (gid >= T_OFF[L + 1]) ++L;
  int local = chunk - T_OFF[L] / 8;
  int lane = local & 63;
  int t = local >> 6;
  int n, k0;
  if (L < 11) {
    int KT = T_KP[L] >> 4;
    int s = t % KT, j = t / KT;
    n = j * 32 + (lane & 31);
    k0 = s * 16 + (lane >> 5) * 8;
  } else {
    int KT = T_KP[L] >> 5;
    int s = t % KT, j = t / KT;
    n = j * 16 + (lane & 15);
    k0 = s * 32 + (lane >> 4) * 8;
  }
  const float* src = a.src[L];
  int K = T_KS[L], Nn = T_NS[L];
  ushort8v o;
#pragma unroll
  for (int i = 0; i < 8; ++i) {
    int k = k0 + i;
    float v = (k < K && n < Nn) ? src[(size_t)k * Nn + n] : 0.f;
    o[i] = f2h(v);
  }
  *reinterpret_cast<ushort8v*>(wt + gid) = o;
}

// ---- kernel 2: fully fused per-point pipeline, 128 pts/block, 512 threads --
// Voxel branch runs PER POINT inside the wave-private 16x16 chain (zero extra
// barriers; weights from global/L2 — each (j,s) fragment is one coalesced
// 1KB line shared by all 8 waves).  R7's block-wide uv layers (+49us) removed.
// bufX[128][XSTR]: x [0,76) | back [76,140) | zero [140,152).
// reg2[128][RSTR] per-row chain cols: pe-gather [192,256) -> uv1 [0,128) ->
//   pcd [192,256); fw1 [128,192); fw2/front [0,64); bw1 [64,128);
//   bw2 [128,192); then n-stack h in [0,256).
// wShare: front-chain weights (16x16x32 layout), staged once per block.
struct MainArgs {
  const float* x;
  const int* inds;
  const int* invmap;
  const unsigned short* wt;
  float* out;
  const float* fb1; const float* fb2;
  const float* ub1; const float* ub2;
  const float* bb1; const float* bb2; const float* bb3;
  const float* nb0; const float* nb2; const float* nb4; const float* nb6; const float* nb8;
};

__global__ __launch_bounds__(512, 2) void main_k(MainArgs a) {
  __shared__ __attribute__((aligned(16))) unsigned short bufX[128 * XSTR];
  __shared__ __attribute__((aligned(16))) unsigned short reg2[128 * RSTR];
  __shared__ __attribute__((aligned(16))) unsigned short wShare[WFRONT_HALFS];
  const int wave = threadIdx.x >> 6, lane = threadIdx.x & 63;
  const int nh = lane & 15, q = lane >> 4;
  const int p0 = blockIdx.x * 128;
  const int rp = wave * 16 + nh;  // this lane's point-row for the chain

  // stage front-chain weights global->LDS (49152 B, 3072 x 16B, 6 per thread)
  {
    const uint4v* gsrc = reinterpret_cast<const uint4v*>(a.wt + OFF_FW1X);
    uint4v* ldst = reinterpret_cast<uint4v*>(wShare);
#pragma unroll
    for (int i = 0; i < 6; ++i)
      ldst[threadIdx.x + i * 512] = gsrc[threadIdx.x + i * 512];
  }

  // stage own 16 rows of x (cols [0,76)) + zero pad [140,152) — wave-private
  for (int idx = lane; idx < 16 * 19; idx += 64) {
    int p = idx / 19, g = idx - p * 19;
    floatx4a f = *reinterpret_cast<const floatx4a*>(
        a.x + (size_t)(p0 + wave * 16 + p) * X_STRIDE + g * 4);
    uint2v hv; hv[0] = pk2(f[0], f[1]); hv[1] = pk2(f[2], f[3]);
    *reinterpret_cast<uint2v*>(bufX + (wave * 16 + p) * XSTR + g * 4) = hv;
  }
  for (int idx = lane; idx < 16 * 3; idx += 64) {
    int p = idx / 3, c = (idx - p * 3) * 4;
    uint2v z; z[0] = 0u; z[1] = 0u;
    *reinterpret_cast<uint2v*>(bufX + (wave * 16 + p) * XSTR + 140 + c) = z;
  }
  // stage double-gathered voxel pe rows -> reg2 cols [192,256) (col 63 pad)
  for (int idx = lane; idx < 16 * 16; idx += 64) {
    int p = idx >> 4, g = idx & 15;
    int r  = a.invmap[p0 + wave * 16 + p];
    int gi = a.inds[r];
    floatx4a f = *reinterpret_cast<const floatx4a*>(
        a.x + (size_t)gi * X_STRIDE + g * 4);
    if (g == 15) f[3] = 0.f;  // pe col 63 is padding (K=63)
    uint2v hv; hv[0] = pk2(f[0], f[1]); hv[1] = pk2(f[2], f[3]);
    *reinterpret_cast<uint2v*>(reg2 + (wave * 16 + p) * RSTR + 192 + g * 4) = hv;
  }
  __syncthreads();  // wShare + x-rows + gathered pe visible

  // ---- wave-private chain (16x16x32): voxel branch + front chain ----
  {
    unsigned short* rowX = bufX + rp * XSTR;
    unsigned short* rowT = reg2 + rp * RSTR;

    // uv1: pe [192,256) -> 128 relu -> [0,128)   (weights from global/L2)
    {
      floatx4 t8[8];
      chainZero<8>(t8);
      chain_mm<8>(t8, rowT + 192, a.wt + OFF_UW1X, 2, 0, 2);
      chain_epi<8>(t8, rowT, a.ub1, true);
    }
    asm volatile("s_waitcnt lgkmcnt(0)" ::: "memory");
    floatx4 t4[4];
    // uv2: [0,128) -> pcd [192,256), no relu      (weights from global/L2)
    chainZero<4>(t4);
    chain_mm<4>(t4, rowT, a.wt + OFF_UW2X, 4, 0, 4);
    chain_epi<4>(t4, rowT + 192, a.ub2, false);
    asm volatile("s_waitcnt lgkmcnt(0)" ::: "memory");
    // fw1: pe(63+pad) -> 64 relu -> [128,192)
    chainZero<4>(t4);
    chain_mm<4>(t4, rowX, wShare + LF_FW1, 2, 0, 2);
    chain_epi<4>(t4, rowT + 128, a.fb1, true);
    asm volatile("s_waitcnt lgkmcnt(0)" ::: "memory");
    // fw2: [128,192) -> front [0,64), no relu
    chainZero<4>(t4);
    chain_mm<4>(t4, rowT + 128, wShare + LF_FW2, 2, 0, 2);
    chain_epi<4>(t4, rowT, a.fb2, false);
    asm volatile("s_waitcnt lgkmcnt(0)" ::: "memory");
    // bw1: [front [0,64) | pcd [192,256)] -> 64 relu -> [64,128)
    chainZero<4>(t4);
    chain_mm<4>(t4, rowT, wShare + LF_BW1, 4, 0, 2);
    chain_mm<4>(t4, rowT + 192, wShare + LF_BW1, 4, 2, 4);
    chain_epi<4>(t4, rowT + 64, a.bb1, true);
    asm volatile("s_waitcnt lgkmcnt(0)" ::: "memory");
    // bw2: [64,128) -> 64 relu -> [128,192)
    chainZero<4>(t4);
    chain_mm<4>(t4, rowT + 64, wShare + LF_BW2, 2, 0, 2);
    chain_epi<4>(t4, rowT + 128, a.bb2, true);
    asm volatile("s_waitcnt lgkmcnt(0)" ::: "memory");
    // bw3: [128,192) -> back -> bufX cols [76,140), no relu
    chainZero<4>(t4);
    chain_mm<4>(t4, rowT + 128, wShare + LF_BW3, 2, 0, 2);
    chain_epi<4>(t4, rowX + 76, a.bb3, false);
  }
  __syncthreads();

  // ---- 256-wide stack: 8 waves, NJ=1 (j=wave), NM=4 (all 128 pts) ----
  // n0: xx(144) -> 256 relu
  {
    floatx16 acc[1][4];
    zero32<1, 4>(acc);
    accum32<1, 4>(acc, bufX, XSTR, 0, a.wt + OFF_NW0, 9, wave, 0, 9, 0);
    epi32<1, 4>(acc, reg2, RSTR, wave * 32, 0, a.nb0, wave * 32, true);
  }
  __syncthreads();
  // n2: 256 -> 256 relu, in-place
  {
    floatx16 acc[1][4];
    zero32<1, 4>(acc);
    accum32<1, 4>(acc, reg2, RSTR, 0, a.wt + OFF_NW2, 16, wave, 0, 16, 0);
    __syncthreads();
    epi32<1, 4>(acc, reg2, RSTR, wave * 32, 0, a.nb2, wave * 32, true);
  }
  __syncthreads();
  // n4: [h(256)|xx(144)] -> 256 relu, in-place
  {
    floatx16 acc[1][4];
    zero32<1, 4>(acc);
    accum32<1, 4>(acc, reg2, RSTR, 0, a.wt + OFF_NW4, 25, wave, 0, 16, 0);
    accum32<1, 4>(acc, bufX, XSTR, 0, a.wt + OFF_NW4, 25, wave, 16, 25, 16);
    __syncthreads();
    epi32<1, 4>(acc, reg2, RSTR, wave * 32, 0, a.nb4, wave * 32, true);
  }
  __syncthreads();
  // n6: 256 -> 256 relu, in-place
  {
    floatx16 acc[1][4];
    zero32<1, 4>(acc);
    accum32<1, 4>(acc, reg2, RSTR, 0, a.wt + OFF_NW6, 16, wave, 0, 16, 0);
    __syncthreads();
    epi32<1, 4>(acc, reg2, RSTR, wave * 32, 0, a.nb6, wave * 32, true);
  }
  __syncthreads();
  // n8: 256 -> 12 via 16x16x32; each wave its own 16 pts; direct global store
  {
    floatx4 acc = {0.f, 0.f, 0.f, 0.f};
    accum16(acc, reg2, RSTR, wave * 16, a.wt + OFF_NW8, 8);
    if (q < 3) {
      floatx4 o;
#pragma unroll
      for (int r = 0; r < 4; ++r) o[r] = acc[r] + a.nb8[q * 4 + r];
      *reinterpret_cast<floatx4*>(a.out + (size_t)(p0 + wave * 16 + nh) * 12 + q * 4) = o;
    }
  }
}

// ---- launch ----------------------------------------------------------------
extern "C" void kernel_launch(void* const* d_in, const int* in_sizes, int n_in,
                              void* d_out, int out_size, void* d_ws, size_t ws_size,
                              hipStream_t stream) {
  const float* x      = (const float*)d_in[0];
  const int*   inds   = (const int*)d_in[1];
  const int*   invmap = (const int*)d_in[2];
  const int M = in_sizes[1];

  unsigned short* wt = (unsigned short*)d_ws;  // 712 KB

  PrepArgs pa;
  pa.src[0]  = (const float*)d_in[3];   // fw1
  pa.src[1]  = (const float*)d_in[5];   // fw2
  pa.src[2]  = (const float*)d_in[7];   // uw1
  pa.src[3]  = (const float*)d_in[9];   // uw2
  pa.src[4]  = (const float*)d_in[11];  // bw1
  pa.src[5]  = (const float*)d_in[13];  // bw2
  pa.src[6]  = (const float*)d_in[15];  // bw3
  pa.src[7]  = (const float*)d_in[17];  // nw0
  pa.src[8]  = (const float*)d_in[19];  // nw2
  pa.src[9]  = (const float*)d_in[21];  // nw4
  pa.src[10] = (const float*)d_in[23];  // nw6
  pa.src[11] = (const float*)d_in[25];  // nw8
  pa.src[12] = (const float*)d_in[3];   // fw1 (16x16x32 layout)
  pa.src[13] = (const float*)d_in[5];   // fw2
  pa.src[14] = (const float*)d_in[11];  // bw1
  pa.src[15] = (const float*)d_in[13];  // bw2
  pa.src[16] = (const float*)d_in[15];  // bw3
  pa.src[17] = (const float*)d_in[7];   // uw1 (16x16x32 layout)
  pa.src[18] = (const float*)d_in[9];   // uw2 (16x16x32 layout)

  float* outM = (float*)d_out + (size_t)N_PTS * 12;
  prep_k<<<(WT_TOTAL / 8 + 255) / 256, 256, 0, stream>>>(pa, wt, outM, (float)M);

  MainArgs ma;
  ma.x = x; ma.inds = inds; ma.invmap = invmap; ma.wt = wt; ma.out = (float*)d_out;
  ma.fb1 = (const float*)d_in[4];  ma.fb2 = (const float*)d_in[6];
  ma.ub1 = (const float*)d_in[8];  ma.ub2 = (const float*)d_in[10];
  ma.bb1 = (const float*)d_in[12]; ma.bb2 = (const float*)d_in[14]; ma.bb3 = (const float*)d_in[16];
  ma.nb0 = (const float*)d_in[18]; ma.nb2 = (const float*)d_in[20];
  ma.nb4 = (const float*)d_in[22]; ma.nb6 = (const float*)d_in[24]; ma.nb8 = (const float*)d_in[26];
  main_k<<<N_PTS / 128, 512, 0, stream>>>(ma);
}

// Round 9
// 357.712 us; speedup vs baseline: 1.0767x; 1.0767x over previous
//
#include <hip/hip_runtime.h>

#define N_PTS 262144
#define X_STRIDE 79

// LDS strides in halfs — 16B-aligned rows (R5 proved odd strides break
// ds_read_b128/ds_write_b64 vectorization, costing 3.4x).
#define RSTR 264   // reg2
#define XSTR 152   // bufX
#define VSTR 72    // bufV
#define USTR 136   // bufU

using floatx4   = __attribute__((ext_vector_type(4))) float;
using floatx4a  = __attribute__((ext_vector_type(4), aligned(4))) float;
using floatx16  = __attribute__((ext_vector_type(16))) float;
using half8     = __attribute__((ext_vector_type(8))) _Float16;
using ushort8v  = __attribute__((ext_vector_type(8))) unsigned short;
using uint2v    = __attribute__((ext_vector_type(2))) unsigned int;
using uint4v    = __attribute__((ext_vector_type(4))) unsigned int;

__device__ __forceinline__ unsigned short f2h(float f) {
  _Float16 h = (_Float16)f;
  return __builtin_bit_cast(unsigned short, h);
}
// pack 2 f32 -> 2 f16 in one VALU op (v_cvt_pkrtz_f16_f32)
__device__ __forceinline__ unsigned int pk2(float a, float b) {
  return __builtin_bit_cast(unsigned int, __builtin_amdgcn_cvt_pkrtz(a, b));
}

// ---- weight table: FRAGMENT-MAJOR fp16 -------------------------------------
// Layers 0..10: 32x32x16 A-layout: chunk (j,s,lane) at off+((j*KT+s)*64+lane)*8
//   holds W^T[j*32+(lane&31)][s*16+(lane>>5)*8+0..7], KT=KP/16.
// Layers 11..16: 16x16x32 A-layout: W^T[j*16+(lane&15)][s*32+(lane>>4)*8+..],
//   KT=KP/32.  (11=nw8; 12..16 = fw1,fw2,bw1,bw2,bw3 duplicates for the
//   wave-private front chain.)
__device__ const int T_KS[17]  = {63,64,63,128,128,64,64,140,256,396,256,256,
                                  63,64,128,64,64};
__device__ const int T_NS[17]  = {64,64,128,64,64,64,64,256,256,256,256,12,
                                  64,64,64,64,64};
__device__ const int T_KP[17]  = {64,64,64,128,128,64,64,144,256,400,256,256,
                                  64,64,128,64,64};
__device__ const int T_OFF[18] = {0,4096,8192,16384,24576,32768,36864,40960,
                                  77824,143360,245760,311296,
                                  315392,319488,323584,331776,335872,339968};
#define OFF_FW1 0
#define OFF_FW2 4096
#define OFF_UW1 8192
#define OFF_UW2 16384
#define OFF_BW1 24576
#define OFF_BW2 32768
#define OFF_BW3 36864
#define OFF_NW0 40960
#define OFF_NW2 77824
#define OFF_NW4 143360
#define OFF_NW6 245760
#define OFF_NW8 311296
#define OFF_FW1X 315392
#define OFF_FW2X 319488
#define OFF_BW1X 323584
#define OFF_BW2X 331776
#define OFF_BW3X 335872
#define WT_TOTAL 339968
// LDS-relative offsets of the staged front-chain weights (halfs)
#define LF_FW1 0
#define LF_FW2 4096
#define LF_BW1 8192
#define LF_BW2 16384
#define LF_BW3 20480
#define WFRONT_HALFS 24576

// ---- 32x32x16 MFMA accum: D(features x points) = W^T(A) x X^T(B) -----------
// B frag: B[k=(lane>>5)*8+i][pt=lane&31] -> LDS row(point)-major 16B read.
// D: col=pt=lane&31, row=feat=(reg&3)+8*(reg>>2)+4*(lane>>5).
// Plain loop — R2-R8 proved every manual scheduling/staging/fusion variant
// is neutral or regresses; the compiler's own interleave is the measured best.
template<int NJ, int NM>
__device__ __forceinline__ void accum32(floatx16 (&acc)[NJ][NM],
    const unsigned short* ldsB, int strideB, int mrow0,
    const unsigned short* wtL, int KTtot, int jg0,
    int sBegin, int sEnd, int sBBase) {
  const int lane = threadIdx.x & 63;
  const int pr = lane & 31, h = lane >> 5;
#pragma unroll 4
  for (int s = sBegin; s < sEnd; ++s) {
    half8 b[NM];
#pragma unroll
    for (int m = 0; m < NM; ++m)
      b[m] = *reinterpret_cast<const half8*>(
          ldsB + (mrow0 + m * 32 + pr) * strideB + (s - sBBase) * 16 + h * 8);
#pragma unroll
    for (int j = 0; j < NJ; ++j) {
      half8 w = *reinterpret_cast<const half8*>(
          wtL + (size_t)(((jg0 + j) * KTtot + s) * 64 + lane) * 8);
#pragma unroll
      for (int m = 0; m < NM; ++m)
        acc[j][m] = __builtin_amdgcn_mfma_f32_32x32x16_f16(w, b[m], acc[j][m], 0, 0, 0);
    }
  }
}

template<int NJ, int NM>
__device__ __forceinline__ void zero32(floatx16 (&acc)[NJ][NM]) {
#pragma unroll
  for (int j = 0; j < NJ; ++j)
#pragma unroll
    for (int m = 0; m < NM; ++m)
#pragma unroll
      for (int r = 0; r < 16; ++r) acc[j][m][r] = 0.f;
}

// epilogue: 4 reg-groups per tile; pkrtz-packed ds_write_b64 each.
template<int NJ, int NM>
__device__ __forceinline__ void epi32(const floatx16 (&acc)[NJ][NM],
    unsigned short* ldsOut, int strideO, int colOff, int mrow0,
    const float* bias, int biasBase, bool relu) {
  const int lane = threadIdx.x & 63;
  const int pr = lane & 31, h = lane >> 5;
#pragma unroll
  for (int j = 0; j < NJ; ++j) {
#pragma unroll
    for (int g = 0; g < 4; ++g) {
      floatx4 b4 = *reinterpret_cast<const floatx4*>(bias + biasBase + j * 32 + g * 8 + h * 4);
#pragma unroll
      for (int m = 0; m < NM; ++m) {
        float v0 = acc[j][m][g * 4 + 0] + b4[0];
        float v1 = acc[j][m][g * 4 + 1] + b4[1];
        float v2 = acc[j][m][g * 4 + 2] + b4[2];
        float v3 = acc[j][m][g * 4 + 3] + b4[3];
        if (relu) {
          v0 = fmaxf(v0, 0.f); v1 = fmaxf(v1, 0.f);
          v2 = fmaxf(v2, 0.f); v3 = fmaxf(v3, 0.f);
        }
        uint2v hv; hv[0] = pk2(v0, v1); hv[1] = pk2(v2, v3);
        *reinterpret_cast<uint2v*>(
            ldsOut + (mrow0 + m * 32 + pr) * strideO + colOff + j * 32 + g * 8 + h * 4) = hv;
      }
    }
  }
}

// ---- 16x16x32 path ---------------------------------------------------------
// A frag: A[feat=j*16+(lane&15)][k=s*32+(lane>>4)*8+i]
// B frag: B[k=(lane>>4)*8+i][pt=lane&15]
// D:      col=pt=lane&15, row=feat=(lane>>4)*4+reg   (verified by nw8 path)
__device__ __forceinline__ void accum16(floatx4& acc,
    const unsigned short* ldsB, int strideB, int mrow0,
    const unsigned short* wtL, int sEnd) {
  const int lane = threadIdx.x & 63;
  const int nh = lane & 15, q = lane >> 4;
#pragma unroll
  for (int s = 0; s < 8; ++s) {
    if (s >= sEnd) break;
    half8 b = *reinterpret_cast<const half8*>(
        ldsB + (mrow0 + nh) * strideB + s * 32 + q * 8);
    half8 w = *reinterpret_cast<const half8*>(
        wtL + (size_t)(s * 64 + lane) * 8);
    acc = __builtin_amdgcn_mfma_f32_16x16x32_f16(w, b, acc, 0, 0, 0);
  }
}

// wave-private front-chain helpers (one wave owns 16 points)
__device__ __forceinline__ void chainZero(floatx4 (&t)[4]) {
#pragma unroll
  for (int j = 0; j < 4; ++j) {
    t[j][0] = 0.f; t[j][1] = 0.f; t[j][2] = 0.f; t[j][3] = 0.f;
  }
}

// rowB = LDS base of this lane's point-row + column base (16B aligned)
__device__ __forceinline__ void chain_mm(floatx4 (&t)[4],
    const unsigned short* rowB, const unsigned short* wtL,
    int KT, int sBegin, int sEnd) {
  const int lane = threadIdx.x & 63;
  const int q = lane >> 4;
#pragma unroll
  for (int s = sBegin; s < sEnd; ++s) {
    half8 b = *reinterpret_cast<const half8*>(rowB + (s - sBegin) * 32 + q * 8);
#pragma unroll
    for (int j = 0; j < 4; ++j) {
      half8 w = *reinterpret_cast<const half8*>(
          wtL + (size_t)((j * KT + s) * 64 + lane) * 8);
      t[j] = __builtin_amdgcn_mfma_f32_16x16x32_f16(w, b, t[j], 0, 0, 0);
    }
  }
}

// D -> own point-row: feat = j*16 + q*4 + r, 1 ds_write_b64 per j
__device__ __forceinline__ void chain_epi(const floatx4 (&t)[4],
    unsigned short* rowOut, const float* bias, bool relu) {
  const int lane = threadIdx.x & 63;
  const int q = lane >> 4;
#pragma unroll
  for (int j = 0; j < 4; ++j) {
    floatx4 b4 = *reinterpret_cast<const floatx4*>(bias + j * 16 + q * 4);
    float v0 = t[j][0] + b4[0], v1 = t[j][1] + b4[1];
    float v2 = t[j][2] + b4[2], v3 = t[j][3] + b4[3];
    if (relu) {
      v0 = fmaxf(v0, 0.f); v1 = fmaxf(v1, 0.f);
      v2 = fmaxf(v2, 0.f); v3 = fmaxf(v3, 0.f);
    }
    uint2v hv; hv[0] = pk2(v0, v1); hv[1] = pk2(v2, v3);
    *reinterpret_cast<uint2v*>(rowOut + j * 16 + q * 4) = hv;
  }
}

// ---- kernel 1: weight repack + scalar output -------------------------------
struct PrepArgs { const float* src[17]; };

__global__ __launch_bounds__(256) void prep_k(PrepArgs a, unsigned short* wt,
                                              float* outM, float Mval) {
  int chunk = blockIdx.x * 256 + threadIdx.x;  // one thread per 8-half chunk
  if (chunk == 0) *outM = Mval;
  if (chunk >= WT_TOTAL / 8) return;
  int gid = chunk * 8;
  int L = 0;
  while (gid >= T_OFF[L + 1]) ++L;
  int local = chunk - T_OFF[L] / 8;
  int lane = local & 63;
  int t = local >> 6;
  int n, k0;
  if (L < 11) {
    int KT = T_KP[L] >> 4;
    int s = t % KT, j = t / KT;
    n = j * 32 + (lane & 31);
    k0 = s * 16 + (lane >> 5) * 8;
  } else {
    int KT = T_KP[L] >> 5;
    int s = t % KT, j = t / KT;
    n = j * 16 + (lane & 15);
    k0 = s * 32 + (lane >> 4) * 8;
  }
  const float* src = a.src[L];
  int K = T_KS[L], Nn = T_NS[L];
  ushort8v o;
#pragma unroll
  for (int i = 0; i < 8; ++i) {
    int k = k0 + i;
    float v = (k < K && n < Nn) ? src[(size_t)k * Nn + n] : 0.f;
    o[i] = f2h(v);
  }
  *reinterpret_cast<ushort8v*>(wt + gid) = o;
}

// ---- kernel 2: voxel branch, 64 voxels/block -------------------------------
__global__ __launch_bounds__(256, 3) void voxel_k(const float* __restrict__ x,
                                                  const int* __restrict__ inds,
                                                  const unsigned short* __restrict__ wt,
                                                  const float* __restrict__ ub1,
                                                  const float* __restrict__ ub2,
                                                  unsigned short* __restrict__ vout, int M) {
  __shared__ __attribute__((aligned(16))) unsigned short bufV[64 * VSTR];
  __shared__ __attribute__((aligned(16))) unsigned short bufU[64 * USTR];
  const int wave = threadIdx.x >> 6, lane = threadIdx.x & 63;
  const int pr = lane & 31, h = lane >> 5;
  const int v0 = blockIdx.x * 64;

  for (int idx = threadIdx.x; idx < 64 * 16; idx += 256) {
    int p = idx >> 4, g = idx & 15;
    int v = v0 + p;
    uint2v hv; hv[0] = 0u; hv[1] = 0u;
    if (v < M) {
      floatx4a f = *reinterpret_cast<const floatx4a*>(
          x + (size_t)inds[v] * X_STRIDE + g * 4);
      if (g == 15) f[3] = 0.f;  // col 63 is padding (K=63)
      hv[0] = pk2(f[0], f[1]); hv[1] = pk2(f[2], f[3]);
    }
    *reinterpret_cast<uint2v*>(bufV + p * VSTR + g * 4) = hv;
  }
  __syncthreads();

  // uw1: 63->128 relu
  {
    floatx16 acc[2][1];
    zero32<2, 1>(acc);
    int jg0 = (wave & 1) * 2, m0 = (wave >> 1) * 32;
    accum32<2, 1>(acc, bufV, VSTR, m0, wt + OFF_UW1, 4, jg0, 0, 4, 0);
    epi32<2, 1>(acc, bufU, USTR, jg0 * 32, m0, ub1, jg0 * 32, true);
  }
  __syncthreads();

  // uw2: 128->64, direct global store (pkrtz-packed b64)
  {
    floatx16 acc[1][1];
    zero32<1, 1>(acc);
    int j = wave & 1, m0 = (wave >> 1) * 32;
    accum32<1, 1>(acc, bufU, USTR, m0, wt + OFF_UW2, 8, j, 0, 8, 0);
    int v = v0 + m0 + pr;
    if (v < M) {
#pragma unroll
      for (int g = 0; g < 4; ++g) {
        floatx4 b4 = *reinterpret_cast<const floatx4*>(ub2 + j * 32 + g * 8 + h * 4);
        uint2v hv;
        hv[0] = pk2(acc[0][0][g * 4 + 0] + b4[0], acc[0][0][g * 4 + 1] + b4[1]);
        hv[1] = pk2(acc[0][0][g * 4 + 2] + b4[2], acc[0][0][g * 4 + 3] + b4[3]);
        *reinterpret_cast<uint2v*>(vout + (size_t)v * 64 + j * 32 + g * 8 + h * 4) = hv;
      }
    }
  }
}

// ---- kernel 3: fused per-point pipeline, 128 pts/block, 512 threads --------
// bufX[128][XSTR]: x [0,76) | back [76,140) | zero [140,152).
// reg2[128][RSTR]: front-chain temps in cols [0,128) (wave-private rows),
//                  then h [0,256) for the 256-wide stack.
// wShare: front-chain weights (16x16x32 layout) staged once per block.
struct MainArgs {
  const float* x;
  const int* invmap;
  const unsigned short* wt;
  const unsigned short* vout;
  float* out;
  const float* fb1; const float* fb2;
  const float* bb1; const float* bb2; const float* bb3;
  const float* nb0; const float* nb2; const float* nb4; const float* nb6; const float* nb8;
};

__global__ __launch_bounds__(512, 2) void main_k(MainArgs a) {
  __shared__ __attribute__((aligned(16))) unsigned short bufX[128 * XSTR];
  __shared__ __attribute__((aligned(16))) unsigned short reg2[128 * RSTR];
  __shared__ __attribute__((aligned(16))) unsigned short wShare[WFRONT_HALFS];
  const int wave = threadIdx.x >> 6, lane = threadIdx.x & 63;
  const int nh = lane & 15, q = lane >> 4;
  const int p0 = blockIdx.x * 128;
  const int rp = wave * 16 + nh;  // this lane's point-row for the front chain

  // pcd prefetch: B-fragments for bw1 s=2,3 straight from global vout
  int vr = a.invmap[p0 + rp];
  half8 bp2 = *reinterpret_cast<const half8*>(a.vout + (size_t)vr * 64 + q * 8);
  half8 bp3 = *reinterpret_cast<const half8*>(a.vout + (size_t)vr * 64 + 32 + q * 8);

  // stage front-chain weights global->LDS (49152 B, 3072 x 16B, 6 per thread)
  {
    const uint4v* gsrc = reinterpret_cast<const uint4v*>(a.wt + OFF_FW1X);
    uint4v* ldst = reinterpret_cast<uint4v*>(wShare);
#pragma unroll
    for (int i = 0; i < 6; ++i)
      ldst[threadIdx.x + i * 512] = gsrc[threadIdx.x + i * 512];
  }

  // stage own 16 rows of x (cols [0,76)) + zero pad [140,152) — wave-private
  for (int idx = lane; idx < 16 * 19; idx += 64) {
    int p = idx / 19, g = idx - p * 19;
    floatx4a f = *reinterpret_cast<const floatx4a*>(
        a.x + (size_t)(p0 + wave * 16 + p) * X_STRIDE + g * 4);
    uint2v hv; hv[0] = pk2(f[0], f[1]); hv[1] = pk2(f[2], f[3]);
    *reinterpret_cast<uint2v*>(bufX + (wave * 16 + p) * XSTR + g * 4) = hv;
  }
  for (int idx = lane; idx < 16 * 3; idx += 64) {
    int p = idx / 3, c = (idx - p * 3) * 4;
    uint2v z; z[0] = 0u; z[1] = 0u;
    *reinterpret_cast<uint2v*>(bufX + (wave * 16 + p) * XSTR + 140 + c) = z;
  }
  __syncthreads();  // wShare visible to all waves; x-rows complete

  // ---- wave-private front chain (16x16x32), no barriers ----
  {
    unsigned short* rowX = bufX + rp * XSTR;
    unsigned short* rowT = reg2 + rp * RSTR;
    floatx4 t4[4];

    // fw1: pe(63+pad) -> 64 relu -> reg2 cols [0,64)
    chainZero(t4);
    chain_mm(t4, rowX, wShare + LF_FW1, 2, 0, 2);
    chain_epi(t4, rowT, a.fb1, true);
    asm volatile("s_waitcnt lgkmcnt(0)" ::: "memory");
    // fw2: -> front, reg2 cols [64,128), no relu
    chainZero(t4);
    chain_mm(t4, rowT, wShare + LF_FW2, 2, 0, 2);
    chain_epi(t4, rowT + 64, a.fb2, false);
    asm volatile("s_waitcnt lgkmcnt(0)" ::: "memory");
    // bw1: [front | pcd(global regs)] -> 64 relu -> cols [0,64)
    chainZero(t4);
    chain_mm(t4, rowT + 64, wShare + LF_BW1, 4, 0, 2);
#pragma unroll
    for (int j = 0; j < 4; ++j) {
      half8 w2 = *reinterpret_cast<const half8*>(
          wShare + LF_BW1 + (size_t)((j * 4 + 2) * 64 + lane) * 8);
      t4[j] = __builtin_amdgcn_mfma_f32_16x16x32_f16(w2, bp2, t4[j], 0, 0, 0);
      half8 w3 = *reinterpret_cast<const half8*>(
          wShare + LF_BW1 + (size_t)((j * 4 + 3) * 64 + lane) * 8);
      t4[j] = __builtin_amdgcn_mfma_f32_16x16x32_f16(w3, bp3, t4[j], 0, 0, 0);
    }
    chain_epi(t4, rowT, a.bb1, true);
    asm volatile("s_waitcnt lgkmcnt(0)" ::: "memory");
    // bw2: -> 64 relu -> cols [64,128)
    chainZero(t4);
    chain_mm(t4, rowT, wShare + LF_BW2, 2, 0, 2);
    chain_epi(t4, rowT + 64, a.bb2, true);
    asm volatile("s_waitcnt lgkmcnt(0)" ::: "memory");
    // bw3: -> back -> bufX cols [76,140), no relu
    chainZero(t4);
    chain_mm(t4, rowT + 64, wShare + LF_BW3, 2, 0, 2);
    chain_epi(t4, rowX + 76, a.bb3, false);
  }
  __syncthreads();

  // ---- 256-wide stack: 8 waves, NJ=1 (j=wave), NM=4 (all 128 pts) ----
  // n0: xx(144) -> 256 relu
  {
    floatx16 acc[1][4];
    zero32<1, 4>(acc);
    accum32<1, 4>(acc, bufX, XSTR, 0, a.wt + OFF_NW0, 9, wave, 0, 9, 0);
    epi32<1, 4>(acc, reg2, RSTR, wave * 32, 0, a.nb0, wave * 32, true);
  }
  __syncthreads();
  // n2: 256 -> 256 relu, in-place
  {
    floatx16 acc[1][4];
    zero32<1, 4>(acc);
    accum32<1, 4>(acc, reg2, RSTR, 0, a.wt + OFF_NW2, 16, wave, 0, 16, 0);
    __syncthreads();
    epi32<1, 4>(acc, reg2, RSTR, wave * 32, 0, a.nb2, wave * 32, true);
  }
  __syncthreads();
  // n4: [h(256)|xx(144)] -> 256 relu, in-place
  {
    floatx16 acc[1][4];
    zero32<1, 4>(acc);
    accum32<1, 4>(acc, reg2, RSTR, 0, a.wt + OFF_NW4, 25, wave, 0, 16, 0);
    accum32<1, 4>(acc, bufX, XSTR, 0, a.wt + OFF_NW4, 25, wave, 16, 25, 16);
    __syncthreads();
    epi32<1, 4>(acc, reg2, RSTR, wave * 32, 0, a.nb4, wave * 32, true);
  }
  __syncthreads();
  // n6: 256 -> 256 relu, in-place
  {
    floatx16 acc[1][4];
    zero32<1, 4>(acc);
    accum32<1, 4>(acc, reg2, RSTR, 0, a.wt + OFF_NW6, 16, wave, 0, 16, 0);
    __syncthreads();
    epi32<1, 4>(acc, reg2, RSTR, wave * 32, 0, a.nb6, wave * 32, true);
  }
  __syncthreads();
  // n8: 256 -> 12 via 16x16x32; each wave its own 16 pts; direct global store
  {
    floatx4 acc = {0.f, 0.f, 0.f, 0.f};
    accum16(acc, reg2, RSTR, wave * 16, a.wt + OFF_NW8, 8);
    if (q < 3) {
      floatx4 o;
#pragma unroll
      for (int r = 0; r < 4; ++r) o[r] = acc[r] + a.nb8[q * 4 + r];
      *reinterpret_cast<floatx4*>(a.out + (size_t)(p0 + wave * 16 + nh) * 12 + q * 4) = o;
    }
  }
}

// ---- launch ----------------------------------------------------------------
extern "C" void kernel_launch(void* const* d_in, const int* in_sizes, int n_in,
                              void* d_out, int out_size, void* d_ws, size_t ws_size,
                              hipStream_t stream) {
  const float* x      = (const float*)d_in[0];
  const int*   inds   = (const int*)d_in[1];
  const int*   invmap = (const int*)d_in[2];
  const int M = in_sizes[1];

  unsigned short* wt   = (unsigned short*)d_ws;                       // 680 KB
  unsigned short* vout = (unsigned short*)((char*)d_ws + (1 << 20));  // M*64*2

  PrepArgs pa;
  pa.src[0]  = (const float*)d_in[3];   // fw1
  pa.src[1]  = (const float*)d_in[5];   // fw2
  pa.src[2]  = (const float*)d_in[7];   // uw1
  pa.src[3]  = (const float*)d_in[9];   // uw2
  pa.src[4]  = (const float*)d_in[11];  // bw1
  pa.src[5]  = (const float*)d_in[13];  // bw2
  pa.src[6]  = (const float*)d_in[15];  // bw3
  pa.src[7]  = (const float*)d_in[17];  // nw0
  pa.src[8]  = (const float*)d_in[19];  // nw2
  pa.src[9]  = (const float*)d_in[21];  // nw4
  pa.src[10] = (const float*)d_in[23];  // nw6
  pa.src[11] = (const float*)d_in[25];  // nw8
  pa.src[12] = (const float*)d_in[3];   // fw1 (16x16x32 layout)
  pa.src[13] = (const float*)d_in[5];   // fw2
  pa.src[14] = (const float*)d_in[11];  // bw1
  pa.src[15] = (const float*)d_in[13];  // bw2
  pa.src[16] = (const float*)d_in[15];  // bw3

  float* outM = (float*)d_out + (size_t)N_PTS * 12;
  prep_k<<<(WT_TOTAL / 8 + 255) / 256, 256, 0, stream>>>(pa, wt, outM, (float)M);

  voxel_k<<<(M + 63) / 64, 256, 0, stream>>>(x, inds, wt,
                                             (const float*)d_in[8],   // ub1
                                             (const float*)d_in[10],  // ub2
                                             vout, M);

  MainArgs ma;
  ma.x = x; ma.invmap = invmap; ma.wt = wt; ma.vout = vout; ma.out = (float*)d_out;
  ma.fb1 = (const float*)d_in[4];  ma.fb2 = (const float*)d_in[6];
  ma.bb1 = (const float*)d_in[12]; ma.bb2 = (const float*)d_in[14]; ma.bb3 = (const float*)d_in[16];
  ma.nb0 = (const float*)d_in[18]; ma.nb2 = (const float*)d_in[20];
  ma.nb4 = (const float*)d_in[22]; ma.nb6 = (const float*)d_in[24]; ma.nb8 = (const float*)d_in[26];
  main_k<<<N_PTS / 128, 512, 0, stream>>>(ma);
}